// Round 1
// baseline (2710.216 us; speedup 1.0000x reference)
//
#include <hip/hip_runtime.h>
#include <hip/hip_bf16.h>

// Problem constants (from reference)
#define IN_DIM 128
#define HID    64
#define OUTF   16
#define NGRAPH 500

// ---------------- GEMM: H[N,F] = X[N,K] @ W[K,F] (no bias here) ----------------
// One block = ROWS rows x F cols = 256 threads. W staged in LDS, X rows in LDS.
// Wave layout: for F=64 each wave is exactly one row -> sX read is wave-uniform
// broadcast, sW read is stride-1 across lanes (2-way bank alias = free).
template<int K, int F>
__global__ __launch_bounds__(256) void gemm_kernel(const float* __restrict__ X,
                                                   const float* __restrict__ W,
                                                   float* __restrict__ H, int N) {
    constexpr int ROWS = 256 / F;
    __shared__ float sW[K * F];
    __shared__ float sX[ROWS][K];
    const int tid = threadIdx.x;
    for (int i = tid; i < K * F; i += 256) sW[i] = W[i];
    const int row0 = blockIdx.x * ROWS;
    for (int i = tid; i < ROWS * K; i += 256) {
        int r = i / K, k = i % K;
        int gr = row0 + r;
        sX[r][k] = (gr < N) ? X[(long long)gr * K + k] : 0.f;
    }
    __syncthreads();
    const int r = tid / F, c = tid % F;
    float acc = 0.f;
#pragma unroll
    for (int k = 0; k < K; ++k) acc += sX[r][k] * sW[k * F + c];
    const int gr = row0 + r;
    if (gr < N) H[(long long)gr * F + c] = acc;
}

// ---------------- degree: degf[dst] += 1 ----------------
__global__ void deg_kernel(const int* __restrict__ dst, float* __restrict__ degf, int E) {
    int e = blockIdx.x * blockDim.x + threadIdx.x;
    if (e < E) atomicAdd(&degf[dst[e]], 1.0f);
}

// ---------------- dis[n] = 1/sqrt(1+deg[n]) (in place) ----------------
__global__ void dis_kernel(float* __restrict__ degf, int N) {
    int n = blockIdx.x * blockDim.x + threadIdx.x;
    if (n < N) degf[n] = 1.0f / sqrtf(1.0f + degf[n]);
}

// ---------------- scatter: agg[dst] += H[src] * dis[src]*dis[dst] ----------------
// One thread per (edge, float4-chunk). Consecutive threads = consecutive chunks
// of the same edge -> gather is a coalesced 64/16-float burst per edge group.
template<int F>
__global__ void scatter_kernel(const float* __restrict__ H, const int* __restrict__ src,
                               const int* __restrict__ dst, const float* __restrict__ dis,
                               float* __restrict__ agg, int E) {
    constexpr int VF = F / 4;
    long long idx = (long long)blockIdx.x * blockDim.x + threadIdx.x;
    long long total = (long long)E * VF;
    if (idx >= total) return;
    int e = (int)(idx >> (VF == 16 ? 4 : 2));
    int c = ((int)idx & (VF - 1)) * 4;
    int s = src[e], d = dst[e];
    float w = dis[s] * dis[d];
    const float4 v = *(const float4*)(H + (long long)s * F + c);
    float* a = agg + (long long)d * F + c;
    atomicAdd(a + 0, v.x * w);
    atomicAdd(a + 1, v.y * w);
    atomicAdd(a + 2, v.z * w);
    atomicAdd(a + 3, v.w * w);
}

// ---------------- combine: agg = [relu](agg + H*dis^2 + b) ----------------
template<int F, bool RELU>
__global__ void combine_kernel(float* __restrict__ agg, const float* __restrict__ H,
                               const float* __restrict__ dis, const float* __restrict__ b,
                               int N) {
    int idx = blockIdx.x * blockDim.x + threadIdx.x;
    if (idx >= N * F) return;
    int n = idx / F, f = idx & (F - 1);
    float di = dis[n];
    float v = agg[idx] + H[idx] * di * di + b[f];
    if (RELU) v = fmaxf(v, 0.f);
    agg[idx] = v;
}

// ---------------- pooling ----------------
__global__ void pool_counts_kernel(const int* __restrict__ batch, float* __restrict__ counts, int N) {
    int n = blockIdx.x * blockDim.x + threadIdx.x;
    if (n < N) atomicAdd(&counts[batch[n]], 1.0f);
}

__global__ void pool_sums_kernel(const float* __restrict__ H, const int* __restrict__ batch,
                                 float* __restrict__ sums, int N) {
    int idx = blockIdx.x * blockDim.x + threadIdx.x;
    if (idx >= N * OUTF) return;
    int n = idx >> 4, f = idx & 15;
    atomicAdd(&sums[batch[n] * OUTF + f], H[idx]);
}

__global__ void divide_kernel(const float* __restrict__ sums, const float* __restrict__ counts,
                              float* __restrict__ out) {
    int i = blockIdx.x * blockDim.x + threadIdx.x;
    if (i < NGRAPH * OUTF) out[i] = sums[i] / fmaxf(counts[i >> 4], 1.0f);
}

extern "C" void kernel_launch(void* const* d_in, const int* in_sizes, int n_in,
                              void* d_out, int out_size, void* d_ws, size_t ws_size,
                              hipStream_t stream) {
    const float* x     = (const float*)d_in[0];
    const int*   ei    = (const int*)d_in[1];
    const int*   batch = (const int*)d_in[2];
    const float* W1 = (const float*)d_in[3];
    const float* b1 = (const float*)d_in[4];
    const float* W2 = (const float*)d_in[5];
    const float* b2 = (const float*)d_in[6];
    const float* W3 = (const float*)d_in[7];
    const float* b3 = (const float*)d_in[8];
    float* out = (float*)d_out;

    const int N = in_sizes[2];          // 100000 nodes
    const int E = in_sizes[1] / 2;      // 1200000 edges
    const int* src = ei;
    const int* dst = ei + E;

    // workspace layout (floats)
    float* ws   = (float*)d_ws;
    float* dis  = ws;                         // N
    float* bufA = dis + N;                    // N*64  (h: pre-aggregation features)
    float* bufB = bufA + (size_t)N * HID;     // N*64  (agg / layer output)
    float* sums = bufB + (size_t)N * HID;     // 500*16
    float* cnts = sums + NGRAPH * OUTF;       // 500

    const int B = 256;

    // degree + dis
    hipMemsetAsync(dis, 0, (size_t)N * sizeof(float), stream);
    deg_kernel<<<(E + B - 1) / B, B, 0, stream>>>(dst, dis, E);
    dis_kernel<<<(N + B - 1) / B, B, 0, stream>>>(dis, N);

    // ---- layer 1: x[N,128] @ W1[128,64] ----
    gemm_kernel<IN_DIM, HID><<<(N + 3) / 4, B, 0, stream>>>(x, W1, bufA, N);
    hipMemsetAsync(bufB, 0, (size_t)N * HID * sizeof(float), stream);
    {
        long long total = (long long)E * (HID / 4);
        scatter_kernel<HID><<<(int)((total + B - 1) / B), B, 0, stream>>>(bufA, src, dst, dis, bufB, E);
    }
    combine_kernel<HID, true><<<(N * HID + B - 1) / B, B, 0, stream>>>(bufB, bufA, dis, b1, N);

    // ---- layer 2: out1[N,64] @ W2[64,64] ----
    gemm_kernel<HID, HID><<<(N + 3) / 4, B, 0, stream>>>(bufB, W2, bufA, N);
    hipMemsetAsync(bufB, 0, (size_t)N * HID * sizeof(float), stream);
    {
        long long total = (long long)E * (HID / 4);
        scatter_kernel<HID><<<(int)((total + B - 1) / B), B, 0, stream>>>(bufA, src, dst, dis, bufB, E);
    }
    combine_kernel<HID, true><<<(N * HID + B - 1) / B, B, 0, stream>>>(bufB, bufA, dis, b2, N);

    // ---- layer 3: out2[N,64] @ W3[64,16] ----
    gemm_kernel<HID, OUTF><<<(N + 15) / 16, B, 0, stream>>>(bufB, W3, bufA, N);
    hipMemsetAsync(bufB, 0, (size_t)N * OUTF * sizeof(float), stream);
    {
        long long total = (long long)E * (OUTF / 4);
        scatter_kernel<OUTF><<<(int)((total + B - 1) / B), B, 0, stream>>>(bufA, src, dst, dis, bufB, E);
    }
    combine_kernel<OUTF, false><<<(N * OUTF + B - 1) / B, B, 0, stream>>>(bufB, bufA, dis, b3, N);

    // ---- global mean pool ----
    hipMemsetAsync(sums, 0, (NGRAPH * OUTF + NGRAPH) * sizeof(float), stream);
    pool_counts_kernel<<<(N + B - 1) / B, B, 0, stream>>>(batch, cnts, N);
    pool_sums_kernel<<<(N * OUTF + B - 1) / B, B, 0, stream>>>(bufB, batch, sums, N);
    divide_kernel<<<(NGRAPH * OUTF + B - 1) / B, B, 0, stream>>>(sums, cnts, out);
}

// Round 2
// 839.976 us; speedup vs baseline: 3.2265x; 3.2265x over previous
//
#include <hip/hip_runtime.h>
#include <hip/hip_bf16.h>

#define IN_DIM 128
#define HID    64
#define OUTF   16
#define NGRAPH 500

// ---------------- GEMM: H[N,F] = X[N,K] @ W[K,F] ----------------
template<int K, int F>
__global__ __launch_bounds__(256) void gemm_kernel(const float* __restrict__ X,
                                                   const float* __restrict__ W,
                                                   float* __restrict__ H, int N) {
    constexpr int ROWS = 256 / F;
    __shared__ float sW[K * F];
    __shared__ float sX[ROWS][K];
    const int tid = threadIdx.x;
    for (int i = tid; i < K * F; i += 256) sW[i] = W[i];
    const int row0 = blockIdx.x * ROWS;
    for (int i = tid; i < ROWS * K; i += 256) {
        int r = i / K, k = i % K;
        int gr = row0 + r;
        sX[r][k] = (gr < N) ? X[(long long)gr * K + k] : 0.f;
    }
    __syncthreads();
    const int r = tid / F, c = tid % F;
    float acc = 0.f;
#pragma unroll
    for (int k = 0; k < K; ++k) acc += sX[r][k] * sW[k * F + c];
    const int gr = row0 + r;
    if (gr < N) H[(long long)gr * F + c] = acc;
}

// ---------------- degree (int) ----------------
__global__ void deg_kernel(const int* __restrict__ dst, int* __restrict__ degi, int E) {
    int e = blockIdx.x * blockDim.x + threadIdx.x;
    if (e < E) atomicAdd(&degi[dst[e]], 1);
}

// ---------------- dis[n] = 1/sqrt(1+deg[n]) ----------------
__global__ void dis_kernel(const int* __restrict__ degi, float* __restrict__ dis, int N) {
    int n = blockIdx.x * blockDim.x + threadIdx.x;
    if (n < N) dis[n] = 1.0f / sqrtf(1.0f + (float)degi[n]);
}

// ---------------- hierarchical exclusive scan of degi -> rowptr ----------------
__global__ __launch_bounds__(1024) void scan1_kernel(const int* __restrict__ degi,
                                                     int* __restrict__ rowptr,
                                                     int* __restrict__ aux, int N) {
    __shared__ int s[1024];
    int i = blockIdx.x * 1024 + threadIdx.x;
    int v = (i < N) ? degi[i] : 0;
    s[threadIdx.x] = v;
    __syncthreads();
    for (int off = 1; off < 1024; off <<= 1) {
        int t = (threadIdx.x >= off) ? s[threadIdx.x - off] : 0;
        __syncthreads();
        s[threadIdx.x] += t;
        __syncthreads();
    }
    if (i < N) rowptr[i] = s[threadIdx.x] - v;          // exclusive
    if (threadIdx.x == 1023) aux[blockIdx.x] = s[1023]; // block total
}

__global__ __launch_bounds__(128) void scan2_kernel(int* __restrict__ aux, int nb) {
    __shared__ int s[128];
    int v = (threadIdx.x < nb) ? aux[threadIdx.x] : 0;
    s[threadIdx.x] = v;
    __syncthreads();
    for (int off = 1; off < 128; off <<= 1) {
        int t = (threadIdx.x >= off) ? s[threadIdx.x - off] : 0;
        __syncthreads();
        s[threadIdx.x] += t;
        __syncthreads();
    }
    if (threadIdx.x < nb) aux[threadIdx.x] = s[threadIdx.x] - v; // exclusive
}

__global__ __launch_bounds__(1024) void scan3_kernel(int* __restrict__ rowptr,
                                                     const int* __restrict__ aux, int N) {
    int i = blockIdx.x * 1024 + threadIdx.x;
    if (i < N) rowptr[i] += aux[blockIdx.x];
}

// ---------------- CSR fill: after this, rowptr[n] == end of bucket n ----------------
__global__ void fill_kernel(const int* __restrict__ src, const int* __restrict__ dst,
                            int* __restrict__ rowptr, int* __restrict__ csr_src, int E) {
    int e = blockIdx.x * blockDim.x + threadIdx.x;
    if (e < E) {
        int d = dst[e];
        int pos = atomicAdd(&rowptr[d], 1);
        csr_src[pos] = src[e];
    }
}

// ---------------- fused aggregate + self-loop + bias [+ relu], F=64 ----------------
// One 64-lane wave per node; lane = feature. Edge/index loads are wave-uniform
// (HW broadcast); H-row gathers are 256B coalesced bursts.
template<bool RELU>
__global__ __launch_bounds__(256) void agg64_kernel(const float* __restrict__ H,
                                                    const int* __restrict__ rowptr,
                                                    const int* __restrict__ csr_src,
                                                    const float* __restrict__ dis,
                                                    const float* __restrict__ b,
                                                    float* __restrict__ out, int N) {
    int node = blockIdx.x * 4 + (threadIdx.x >> 6);
    int lane = threadIdx.x & 63;
    if (node >= N) return;
    float dd = dis[node];
    float acc = H[(long long)node * HID + lane] * dd * dd;
    int i0 = (node == 0) ? 0 : rowptr[node - 1];
    int i1 = rowptr[node];
    for (int i = i0; i < i1; ++i) {
        int s = csr_src[i];
        float w = dis[s] * dd;
        acc += H[(long long)s * HID + lane] * w;
    }
    acc += b[lane];
    if (RELU) acc = fmaxf(acc, 0.f);
    out[(long long)node * HID + lane] = acc;
}

// ---------------- same for F=16: 16-lane group per node ----------------
template<bool RELU>
__global__ __launch_bounds__(256) void agg16_kernel(const float* __restrict__ H,
                                                    const int* __restrict__ rowptr,
                                                    const int* __restrict__ csr_src,
                                                    const float* __restrict__ dis,
                                                    const float* __restrict__ b,
                                                    float* __restrict__ out, int N) {
    int node = blockIdx.x * 16 + (threadIdx.x >> 4);
    int lane = threadIdx.x & 15;
    if (node >= N) return;
    float dd = dis[node];
    float acc = H[(long long)node * OUTF + lane] * dd * dd;
    int i0 = (node == 0) ? 0 : rowptr[node - 1];
    int i1 = rowptr[node];
    for (int i = i0; i < i1; ++i) {
        int s = csr_src[i];
        float w = dis[s] * dd;
        acc += H[(long long)s * OUTF + lane] * w;
    }
    acc += b[lane];
    if (RELU) acc = fmaxf(acc, 0.f);
    out[(long long)node * OUTF + lane] = acc;
}

// ---------------- pooling ----------------
__global__ void pool_counts_kernel(const int* __restrict__ batch, float* __restrict__ counts, int N) {
    int n = blockIdx.x * blockDim.x + threadIdx.x;
    if (n < N) atomicAdd(&counts[batch[n]], 1.0f);
}

__global__ void pool_sums_kernel(const float* __restrict__ H, const int* __restrict__ batch,
                                 float* __restrict__ sums, int N) {
    int idx = blockIdx.x * blockDim.x + threadIdx.x;
    if (idx >= N * OUTF) return;
    int n = idx >> 4, f = idx & 15;
    atomicAdd(&sums[batch[n] * OUTF + f], H[idx]);
}

__global__ void divide_kernel(const float* __restrict__ sums, const float* __restrict__ counts,
                              float* __restrict__ out) {
    int i = blockIdx.x * blockDim.x + threadIdx.x;
    if (i < NGRAPH * OUTF) out[i] = sums[i] / fmaxf(counts[i >> 4], 1.0f);
}

extern "C" void kernel_launch(void* const* d_in, const int* in_sizes, int n_in,
                              void* d_out, int out_size, void* d_ws, size_t ws_size,
                              hipStream_t stream) {
    const float* x     = (const float*)d_in[0];
    const int*   ei    = (const int*)d_in[1];
    const int*   batch = (const int*)d_in[2];
    const float* W1 = (const float*)d_in[3];
    const float* b1 = (const float*)d_in[4];
    const float* W2 = (const float*)d_in[5];
    const float* b2 = (const float*)d_in[6];
    const float* W3 = (const float*)d_in[7];
    const float* b3 = (const float*)d_in[8];
    float* out = (float*)d_out;

    const int N = in_sizes[2];          // 100000
    const int E = in_sizes[1] / 2;      // 1200000
    const int* src = ei;
    const int* dst = ei + E;

    // workspace layout (4-byte units)
    float* ws      = (float*)d_ws;
    float* dis     = ws;                          // N floats
    float* bufA    = dis + N;                     // N*64
    float* bufB    = bufA + (size_t)N * HID;      // N*64
    float* sums    = bufB + (size_t)N * HID;      // 500*16
    float* cnts    = sums + NGRAPH * OUTF;        // 500
    int*   degi    = (int*)(cnts + NGRAPH);       // N ints
    int*   rowptr  = degi + N;                    // N ints
    int*   csr_src = rowptr + N;                  // E ints
    int*   aux     = csr_src + E;                 // <=128 ints

    const int B = 256;
    const int nb = (N + 1023) / 1024;   // scan blocks (<=128)

    // ---- degree, dis, CSR build ----
    hipMemsetAsync(degi, 0, (size_t)N * sizeof(int), stream);
    deg_kernel<<<(E + B - 1) / B, B, 0, stream>>>(dst, degi, E);
    dis_kernel<<<(N + B - 1) / B, B, 0, stream>>>(degi, dis, N);
    scan1_kernel<<<nb, 1024, 0, stream>>>(degi, rowptr, aux, N);
    scan2_kernel<<<1, 128, 0, stream>>>(aux, nb);
    scan3_kernel<<<nb, 1024, 0, stream>>>(rowptr, aux, N);
    fill_kernel<<<(E + B - 1) / B, B, 0, stream>>>(src, dst, rowptr, csr_src, E);
    // now rowptr[n] = end of bucket n; start = rowptr[n-1] (0 for n==0)

    // ---- layer 1 ----
    gemm_kernel<IN_DIM, HID><<<(N + 3) / 4, B, 0, stream>>>(x, W1, bufA, N);
    agg64_kernel<true><<<(N + 3) / 4, B, 0, stream>>>(bufA, rowptr, csr_src, dis, b1, bufB, N);

    // ---- layer 2 ----
    gemm_kernel<HID, HID><<<(N + 3) / 4, B, 0, stream>>>(bufB, W2, bufA, N);
    agg64_kernel<true><<<(N + 3) / 4, B, 0, stream>>>(bufA, rowptr, csr_src, dis, b2, bufB, N);

    // ---- layer 3 ----
    gemm_kernel<HID, OUTF><<<(N + 15) / 16, B, 0, stream>>>(bufB, W3, bufA, N);
    agg16_kernel<false><<<(N + 15) / 16, B, 0, stream>>>(bufA, rowptr, csr_src, dis, b3, bufB, N);

    // ---- global mean pool ----
    hipMemsetAsync(sums, 0, (NGRAPH * OUTF + NGRAPH) * sizeof(float), stream);
    pool_counts_kernel<<<(N + B - 1) / B, B, 0, stream>>>(batch, cnts, N);
    pool_sums_kernel<<<(N * OUTF + B - 1) / B, B, 0, stream>>>(bufB, batch, sums, N);
    divide_kernel<<<(NGRAPH * OUTF + B - 1) / B, B, 0, stream>>>(sums, cnts, out);
}

// Round 3
// 474.549 us; speedup vs baseline: 5.7111x; 1.7701x over previous
//
#include <hip/hip_runtime.h>
#include <hip/hip_bf16.h>

#define IN_DIM 128
#define HID    64
#define OUTF   16
#define NGRAPH 500

// ---------------- GEMM: H[N,F] = X[N,K] @ W[K,F] ----------------
// Each thread computes a float4 of outputs: 1 ds_read_b128 (W) + 1 broadcast
// ds_read_b32 (X) + 4 FMA per k.
template<int K, int F>
__global__ __launch_bounds__(256) void gemm_kernel(const float* __restrict__ X,
                                                   const float* __restrict__ W,
                                                   float* __restrict__ H, int N) {
    constexpr int C4 = F / 4;          // float4 cols
    constexpr int ROWS = 256 / C4;     // rows per block
    constexpr int K4 = K / 4;
    __shared__ float4 sW[K * C4];
    __shared__ float4 sX4[ROWS * K4];
    const int tid = threadIdx.x;
    const float4* W4 = (const float4*)W;
    for (int i = tid; i < K * C4; i += 256) sW[i] = W4[i];
    const int row0 = blockIdx.x * ROWS;
    const float4* X4 = (const float4*)X;
    for (int i = tid; i < ROWS * K4; i += 256) {
        int r = i / K4, kk = i - r * K4;
        int gr = row0 + r;
        float4 z = {0.f, 0.f, 0.f, 0.f};
        sX4[r * K4 + kk] = (gr < N) ? X4[(long long)gr * K4 + kk] : z;
    }
    __syncthreads();
    const int r = tid / C4, c4 = tid - (tid / C4) * C4;
    const float* sXr = (const float*)&sX4[r * K4];
    float4 acc = {0.f, 0.f, 0.f, 0.f};
#pragma unroll
    for (int k = 0; k < K; ++k) {
        float xv = sXr[k];
        float4 wv = sW[k * C4 + c4];
        acc.x += xv * wv.x; acc.y += xv * wv.y;
        acc.z += xv * wv.z; acc.w += xv * wv.w;
    }
    const int gr = row0 + r;
    if (gr < N) ((float4*)H)[(long long)gr * C4 + c4] = acc;
}

// ---------------- degree (int) ----------------
__global__ void deg_kernel(const int* __restrict__ dst, int* __restrict__ degi, int E) {
    int e = blockIdx.x * blockDim.x + threadIdx.x;
    if (e < E) atomicAdd(&degi[dst[e]], 1);
}

// ---------------- dis[n] = 1/sqrt(1+deg[n]) ----------------
__global__ void dis_kernel(const int* __restrict__ degi, float* __restrict__ dis, int N) {
    int n = blockIdx.x * blockDim.x + threadIdx.x;
    if (n < N) dis[n] = 1.0f / sqrtf(1.0f + (float)degi[n]);
}

// ---------------- hierarchical exclusive scan of degi -> rowptr ----------------
__global__ __launch_bounds__(1024) void scan1_kernel(const int* __restrict__ degi,
                                                     int* __restrict__ rowptr,
                                                     int* __restrict__ aux, int N) {
    __shared__ int s[1024];
    int i = blockIdx.x * 1024 + threadIdx.x;
    int v = (i < N) ? degi[i] : 0;
    s[threadIdx.x] = v;
    __syncthreads();
    for (int off = 1; off < 1024; off <<= 1) {
        int t = (threadIdx.x >= off) ? s[threadIdx.x - off] : 0;
        __syncthreads();
        s[threadIdx.x] += t;
        __syncthreads();
    }
    if (i < N) rowptr[i] = s[threadIdx.x] - v;          // exclusive
    if (threadIdx.x == 1023) aux[blockIdx.x] = s[1023]; // block total
}

__global__ __launch_bounds__(128) void scan2_kernel(int* __restrict__ aux, int nb) {
    __shared__ int s[128];
    int v = (threadIdx.x < nb) ? aux[threadIdx.x] : 0;
    s[threadIdx.x] = v;
    __syncthreads();
    for (int off = 1; off < 128; off <<= 1) {
        int t = (threadIdx.x >= off) ? s[threadIdx.x - off] : 0;
        __syncthreads();
        s[threadIdx.x] += t;
        __syncthreads();
    }
    if (threadIdx.x < nb) aux[threadIdx.x] = s[threadIdx.x] - v; // exclusive
}

__global__ __launch_bounds__(1024) void scan3_kernel(int* __restrict__ rowptr,
                                                     const int* __restrict__ aux, int N) {
    int i = blockIdx.x * 1024 + threadIdx.x;
    if (i < N) rowptr[i] += aux[blockIdx.x];
}

// ---------------- CSR fill: after this, rowptr[n] == end of bucket n ----------------
__global__ void fill_kernel(const int* __restrict__ src, const int* __restrict__ dst,
                            int* __restrict__ rowptr, int* __restrict__ csr_src, int E) {
    int e = blockIdx.x * blockDim.x + threadIdx.x;
    if (e < E) {
        int d = dst[e];
        int pos = atomicAdd(&rowptr[d], 1);
        csr_src[pos] = src[e];
    }
}

// ---------------- fused aggregate + self-loop + bias [+ relu], F=64 ----------------
// Wave = one node. 4 edge-groups x 16 float4-chunks: 4 edges in flight per
// iteration, 16B/lane gathers; butterfly-reduce groups at the end.
template<bool RELU>
__global__ __launch_bounds__(256) void agg64_kernel(const float4* __restrict__ H4,
                                                    const int* __restrict__ rowptr,
                                                    const int* __restrict__ csr_src,
                                                    const float* __restrict__ dis,
                                                    const float4* __restrict__ b4,
                                                    float4* __restrict__ out4, int N) {
    int node = blockIdx.x * 4 + (threadIdx.x >> 6);
    int lane = threadIdx.x & 63;
    int g = lane >> 4, c = lane & 15;
    if (node >= N) return;
    float dd = dis[node];
    int i0 = (node == 0) ? 0 : rowptr[node - 1];
    int i1 = rowptr[node];
    float4 acc = {0.f, 0.f, 0.f, 0.f};
    for (int i = i0 + g; i < i1; i += 4) {
        int s = csr_src[i];
        float w = dis[s] * dd;
        float4 v = H4[(long long)s * 16 + c];
        acc.x += v.x * w; acc.y += v.y * w;
        acc.z += v.z * w; acc.w += v.w * w;
    }
#pragma unroll
    for (int m = 16; m <= 32; m <<= 1) {
        acc.x += __shfl_xor(acc.x, m);
        acc.y += __shfl_xor(acc.y, m);
        acc.z += __shfl_xor(acc.z, m);
        acc.w += __shfl_xor(acc.w, m);
    }
    float4 h = H4[(long long)node * 16 + c];
    float sl = dd * dd;
    float4 bb = b4[c];
    acc.x += h.x * sl + bb.x; acc.y += h.y * sl + bb.y;
    acc.z += h.z * sl + bb.z; acc.w += h.w * sl + bb.w;
    if (RELU) {
        acc.x = fmaxf(acc.x, 0.f); acc.y = fmaxf(acc.y, 0.f);
        acc.z = fmaxf(acc.z, 0.f); acc.w = fmaxf(acc.w, 0.f);
    }
    if (g == 0) out4[(long long)node * 16 + c] = acc;
}

// ---------------- same for F=16: 16 edge-groups x 4 chunks per wave ----------------
template<bool RELU>
__global__ __launch_bounds__(256) void agg16_kernel(const float4* __restrict__ H4,
                                                    const int* __restrict__ rowptr,
                                                    const int* __restrict__ csr_src,
                                                    const float* __restrict__ dis,
                                                    const float4* __restrict__ b4,
                                                    float4* __restrict__ out4, int N) {
    int node = blockIdx.x * 4 + (threadIdx.x >> 6);
    int lane = threadIdx.x & 63;
    int g = lane >> 2, c = lane & 3;
    if (node >= N) return;
    float dd = dis[node];
    int i0 = (node == 0) ? 0 : rowptr[node - 1];
    int i1 = rowptr[node];
    float4 acc = {0.f, 0.f, 0.f, 0.f};
    for (int i = i0 + g; i < i1; i += 16) {
        int s = csr_src[i];
        float w = dis[s] * dd;
        float4 v = H4[(long long)s * 4 + c];
        acc.x += v.x * w; acc.y += v.y * w;
        acc.z += v.z * w; acc.w += v.w * w;
    }
#pragma unroll
    for (int m = 4; m <= 32; m <<= 1) {
        acc.x += __shfl_xor(acc.x, m);
        acc.y += __shfl_xor(acc.y, m);
        acc.z += __shfl_xor(acc.z, m);
        acc.w += __shfl_xor(acc.w, m);
    }
    float4 h = H4[(long long)node * 4 + c];
    float sl = dd * dd;
    float4 bb = b4[c];
    acc.x += h.x * sl + bb.x; acc.y += h.y * sl + bb.y;
    acc.z += h.z * sl + bb.z; acc.w += h.w * sl + bb.w;
    if (RELU) {
        acc.x = fmaxf(acc.x, 0.f); acc.y = fmaxf(acc.y, 0.f);
        acc.z = fmaxf(acc.z, 0.f); acc.w = fmaxf(acc.w, 0.f);
    }
    if (g == 0) out4[(long long)node * 4 + c] = acc;
}

// ---------------- pooling: register runs -> LDS bins -> few global atomics ----
// Block covers 256 sorted nodes (span of graphs per block is ~2-3; LDS cap 16
// with global-atomic fallback). Thread = (node-lane, float4-chunk).
__global__ __launch_bounds__(256) void pool_kernel(const float4* __restrict__ H4,
                                                   const int* __restrict__ batch,
                                                   float* __restrict__ sums,
                                                   float* __restrict__ cnts, int N) {
    __shared__ float sBin[16][16];
    __shared__ float sCnt[16];
    const int t = threadIdx.x;
    sBin[t >> 4][t & 15] = 0.f;
    if (t < 16) sCnt[t] = 0.f;
    __syncthreads();
    const int n0 = blockIdx.x * 256;
    const int g0 = batch[n0];
    const int nl = t >> 2;     // node lane 0..63
    const int f4 = t & 3;      // float4 chunk 0..3
    float4 acc = {0.f, 0.f, 0.f, 0.f};
    float cnt = 0.f;
    int curli = -1;
    for (int j = 0; j < 4; ++j) {
        int node = n0 + nl * 4 + j;
        if (node >= N) break;
        int li = batch[node] - g0;
        if (li != curli) {
            if (curli >= 0) {
                if (curli < 16) {
                    float* bp = &sBin[curli][f4 * 4];
                    atomicAdd(bp + 0, acc.x); atomicAdd(bp + 1, acc.y);
                    atomicAdd(bp + 2, acc.z); atomicAdd(bp + 3, acc.w);
                    if (f4 == 0) atomicAdd(&sCnt[curli], cnt);
                } else {
                    float* gp = &sums[(g0 + curli) * OUTF + f4 * 4];
                    atomicAdd(gp + 0, acc.x); atomicAdd(gp + 1, acc.y);
                    atomicAdd(gp + 2, acc.z); atomicAdd(gp + 3, acc.w);
                    if (f4 == 0) atomicAdd(&cnts[g0 + curli], cnt);
                }
            }
            acc.x = acc.y = acc.z = acc.w = 0.f; cnt = 0.f; curli = li;
        }
        float4 v = H4[(long long)node * 4 + f4];
        acc.x += v.x; acc.y += v.y; acc.z += v.z; acc.w += v.w;
        cnt += 1.f;
    }
    if (curli >= 0) {
        if (curli < 16) {
            float* bp = &sBin[curli][f4 * 4];
            atomicAdd(bp + 0, acc.x); atomicAdd(bp + 1, acc.y);
            atomicAdd(bp + 2, acc.z); atomicAdd(bp + 3, acc.w);
            if (f4 == 0) atomicAdd(&sCnt[curli], cnt);
        } else {
            float* gp = &sums[(g0 + curli) * OUTF + f4 * 4];
            atomicAdd(gp + 0, acc.x); atomicAdd(gp + 1, acc.y);
            atomicAdd(gp + 2, acc.z); atomicAdd(gp + 3, acc.w);
            if (f4 == 0) atomicAdd(&cnts[g0 + curli], cnt);
        }
    }
    __syncthreads();
    int bg = t >> 4, bf = t & 15;
    int g = g0 + bg;
    if (g < NGRAPH) {
        float v = sBin[bg][bf];
        if (v != 0.f) atomicAdd(&sums[g * OUTF + bf], v);
        if (bf == 0) {
            float c = sCnt[bg];
            if (c != 0.f) atomicAdd(&cnts[g], c);
        }
    }
}

__global__ void divide_kernel(const float* __restrict__ sums, const float* __restrict__ counts,
                              float* __restrict__ out) {
    int i = blockIdx.x * blockDim.x + threadIdx.x;
    if (i < NGRAPH * OUTF) out[i] = sums[i] / fmaxf(counts[i >> 4], 1.0f);
}

extern "C" void kernel_launch(void* const* d_in, const int* in_sizes, int n_in,
                              void* d_out, int out_size, void* d_ws, size_t ws_size,
                              hipStream_t stream) {
    const float* x     = (const float*)d_in[0];
    const int*   ei    = (const int*)d_in[1];
    const int*   batch = (const int*)d_in[2];
    const float* W1 = (const float*)d_in[3];
    const float* b1 = (const float*)d_in[4];
    const float* W2 = (const float*)d_in[5];
    const float* b2 = (const float*)d_in[6];
    const float* W3 = (const float*)d_in[7];
    const float* b3 = (const float*)d_in[8];
    float* out = (float*)d_out;

    const int N = in_sizes[2];          // 100000
    const int E = in_sizes[1] / 2;      // 1200000
    const int* src = ei;
    const int* dst = ei + E;

    // workspace layout (4-byte units)
    float* ws      = (float*)d_ws;
    float* dis     = ws;                          // N floats
    float* bufA    = dis + N;                     // N*64
    float* bufB    = bufA + (size_t)N * HID;      // N*64
    float* sums    = bufB + (size_t)N * HID;      // 500*16
    float* cnts    = sums + NGRAPH * OUTF;        // 500
    int*   degi    = (int*)(cnts + NGRAPH);       // N ints
    int*   rowptr  = degi + N;                    // N ints
    int*   csr_src = rowptr + N;                  // E ints
    int*   aux     = csr_src + E;                 // <=128 ints

    const int B = 256;
    const int nb = (N + 1023) / 1024;

    // ---- degree, dis, CSR build ----
    hipMemsetAsync(degi, 0, (size_t)N * sizeof(int), stream);
    deg_kernel<<<(E + B - 1) / B, B, 0, stream>>>(dst, degi, E);
    dis_kernel<<<(N + B - 1) / B, B, 0, stream>>>(degi, dis, N);
    scan1_kernel<<<nb, 1024, 0, stream>>>(degi, rowptr, aux, N);
    scan2_kernel<<<1, 128, 0, stream>>>(aux, nb);
    scan3_kernel<<<nb, 1024, 0, stream>>>(rowptr, aux, N);
    fill_kernel<<<(E + B - 1) / B, B, 0, stream>>>(src, dst, rowptr, csr_src, E);

    // ---- layer 1 ----
    gemm_kernel<IN_DIM, HID><<<(N + 15) / 16, B, 0, stream>>>(x, W1, bufA, N);
    agg64_kernel<true><<<(N + 3) / 4, B, 0, stream>>>((const float4*)bufA, rowptr, csr_src,
                                                      dis, (const float4*)b1, (float4*)bufB, N);

    // ---- layer 2 ----
    gemm_kernel<HID, HID><<<(N + 15) / 16, B, 0, stream>>>(bufB, W2, bufA, N);
    agg64_kernel<true><<<(N + 3) / 4, B, 0, stream>>>((const float4*)bufA, rowptr, csr_src,
                                                      dis, (const float4*)b2, (float4*)bufB, N);

    // ---- layer 3 ----
    gemm_kernel<HID, OUTF><<<(N + 63) / 64, B, 0, stream>>>(bufB, W3, bufA, N);
    agg16_kernel<false><<<(N + 3) / 4, B, 0, stream>>>((const float4*)bufA, rowptr, csr_src,
                                                       dis, (const float4*)b3, (float4*)bufB, N);

    // ---- global mean pool ----
    hipMemsetAsync(sums, 0, (NGRAPH * OUTF + NGRAPH) * sizeof(float), stream);
    pool_kernel<<<(N + 255) / 256, B, 0, stream>>>((const float4*)bufB, batch, sums, cnts, N);
    divide_kernel<<<(NGRAPH * OUTF + B - 1) / B, B, 0, stream>>>(sums, cnts, out);
}

// Round 4
// 460.608 us; speedup vs baseline: 5.8840x; 1.0303x over previous
//
#include <hip/hip_runtime.h>
#include <hip/hip_bf16.h>

#define IN_DIM 128
#define HID    64
#define OUTF   16
#define NGRAPH 500

// ---------------- GEMM: H[N,F] = X[N,K] @ W[K,F] ----------------
template<int K, int F>
__global__ __launch_bounds__(256) void gemm_kernel(const float* __restrict__ X,
                                                   const float* __restrict__ W,
                                                   float* __restrict__ H, int N) {
    constexpr int C4 = F / 4;          // float4 cols
    constexpr int ROWS = 256 / C4;     // rows per block
    constexpr int K4 = K / 4;
    __shared__ float4 sW[K * C4];
    __shared__ float4 sX4[ROWS * K4];
    const int tid = threadIdx.x;
    const float4* W4 = (const float4*)W;
    for (int i = tid; i < K * C4; i += 256) sW[i] = W4[i];
    const int row0 = blockIdx.x * ROWS;
    const float4* X4 = (const float4*)X;
    for (int i = tid; i < ROWS * K4; i += 256) {
        int r = i / K4, kk = i - r * K4;
        int gr = row0 + r;
        float4 z = {0.f, 0.f, 0.f, 0.f};
        sX4[r * K4 + kk] = (gr < N) ? X4[(long long)gr * K4 + kk] : z;
    }
    __syncthreads();
    const int r = tid / C4, c4 = tid - (tid / C4) * C4;
    const float* sXr = (const float*)&sX4[r * K4];
    float4 acc = {0.f, 0.f, 0.f, 0.f};
#pragma unroll
    for (int k = 0; k < K; ++k) {
        float xv = sXr[k];
        float4 wv = sW[k * C4 + c4];
        acc.x += xv * wv.x; acc.y += xv * wv.y;
        acc.z += xv * wv.z; acc.w += xv * wv.w;
    }
    const int gr = row0 + r;
    if (gr < N) ((float4*)H)[(long long)gr * C4 + c4] = acc;
}

// ---------------- degree (int), 8 edges/thread ----------------
template<int EPT>
__global__ __launch_bounds__(256) void deg_kernel(const int* __restrict__ dst,
                                                  int* __restrict__ degi, int E) {
    int base = blockIdx.x * (256 * EPT) + threadIdx.x;
    if (base + (EPT - 1) * 256 < E) {
        int d[EPT];
#pragma unroll
        for (int k = 0; k < EPT; ++k) d[k] = dst[base + k * 256];
#pragma unroll
        for (int k = 0; k < EPT; ++k) atomicAdd(&degi[d[k]], 1);
    } else {
#pragma unroll
        for (int k = 0; k < EPT; ++k) {
            int e = base + k * 256;
            if (e < E) atomicAdd(&degi[dst[e]], 1);
        }
    }
}

// ---------------- dis[n] = 1/sqrt(1+deg[n]) ----------------
__global__ void dis_kernel(const int* __restrict__ degi, float* __restrict__ dis, int N) {
    int n = blockIdx.x * blockDim.x + threadIdx.x;
    if (n < N) dis[n] = 1.0f / sqrtf(1.0f + (float)degi[n]);
}

// ---------------- hierarchical exclusive scan of degi -> rowptr ----------------
__global__ __launch_bounds__(1024) void scan1_kernel(const int* __restrict__ degi,
                                                     int* __restrict__ rowptr,
                                                     int* __restrict__ aux, int N) {
    __shared__ int s[1024];
    int i = blockIdx.x * 1024 + threadIdx.x;
    int v = (i < N) ? degi[i] : 0;
    s[threadIdx.x] = v;
    __syncthreads();
    for (int off = 1; off < 1024; off <<= 1) {
        int t = (threadIdx.x >= off) ? s[threadIdx.x - off] : 0;
        __syncthreads();
        s[threadIdx.x] += t;
        __syncthreads();
    }
    if (i < N) rowptr[i] = s[threadIdx.x] - v;          // exclusive
    if (threadIdx.x == 1023) aux[blockIdx.x] = s[1023]; // block total
}

__global__ __launch_bounds__(128) void scan2_kernel(int* __restrict__ aux, int nb) {
    __shared__ int s[128];
    int v = (threadIdx.x < nb) ? aux[threadIdx.x] : 0;
    s[threadIdx.x] = v;
    __syncthreads();
    for (int off = 1; off < 128; off <<= 1) {
        int t = (threadIdx.x >= off) ? s[threadIdx.x - off] : 0;
        __syncthreads();
        s[threadIdx.x] += t;
        __syncthreads();
    }
    if (threadIdx.x < nb) aux[threadIdx.x] = s[threadIdx.x] - v; // exclusive
}

__global__ __launch_bounds__(1024) void scan3_kernel(int* __restrict__ rowptr,
                                                     const int* __restrict__ aux, int N) {
    int i = blockIdx.x * 1024 + threadIdx.x;
    if (i < N) rowptr[i] += aux[blockIdx.x];
}

// ---------------- CSR fill, 8 edges/thread, phase-split for MLP ----------------
// After this, rowptr[n] == end of bucket n.
template<int EPT>
__global__ __launch_bounds__(256) void fill_kernel(const int* __restrict__ src,
                                                   const int* __restrict__ dst,
                                                   int* __restrict__ rowptr,
                                                   int* __restrict__ csr_src, int E) {
    int base = blockIdx.x * (256 * EPT) + threadIdx.x;
    if (base + (EPT - 1) * 256 < E) {
        int s[EPT], d[EPT], pos[EPT];
#pragma unroll
        for (int k = 0; k < EPT; ++k) {
            d[k] = dst[base + k * 256];
            s[k] = src[base + k * 256];
        }
#pragma unroll
        for (int k = 0; k < EPT; ++k) pos[k] = atomicAdd(&rowptr[d[k]], 1);
#pragma unroll
        for (int k = 0; k < EPT; ++k) csr_src[pos[k]] = s[k];
    } else {
#pragma unroll
        for (int k = 0; k < EPT; ++k) {
            int e = base + k * 256;
            if (e < E) {
                int pos = atomicAdd(&rowptr[dst[e]], 1);
                csr_src[pos] = src[e];
            }
        }
    }
}

// ---------------- fused aggregate + self-loop + bias [+ relu], F=64 ----------------
// Wave = one node. 8 edge-groups x 8 lanes x 32B/lane: 8 edges in flight.
template<bool RELU>
__global__ __launch_bounds__(256) void agg64_kernel(const float4* __restrict__ H4,
                                                    const int* __restrict__ rowptr,
                                                    const int* __restrict__ csr_src,
                                                    const float* __restrict__ dis,
                                                    const float4* __restrict__ b4,
                                                    float4* __restrict__ out4, int N) {
    int node = blockIdx.x * 4 + (threadIdx.x >> 6);
    int lane = threadIdx.x & 63;
    int g = lane >> 3, c = lane & 7;   // group, chunk-pair index
    if (node >= N) return;
    float dd = dis[node];
    int i0 = (node == 0) ? 0 : rowptr[node - 1];
    int i1 = rowptr[node];
    float4 a0 = {0.f, 0.f, 0.f, 0.f}, a1 = {0.f, 0.f, 0.f, 0.f};
    for (int i = i0 + g; i < i1; i += 8) {
        int s = csr_src[i];
        float w = dis[s] * dd;
        float4 v0 = H4[(long long)s * 16 + 2 * c];
        float4 v1 = H4[(long long)s * 16 + 2 * c + 1];
        a0.x += v0.x * w; a0.y += v0.y * w; a0.z += v0.z * w; a0.w += v0.w * w;
        a1.x += v1.x * w; a1.y += v1.y * w; a1.z += v1.z * w; a1.w += v1.w * w;
    }
#pragma unroll
    for (int m = 8; m <= 32; m <<= 1) {
        a0.x += __shfl_xor(a0.x, m); a0.y += __shfl_xor(a0.y, m);
        a0.z += __shfl_xor(a0.z, m); a0.w += __shfl_xor(a0.w, m);
        a1.x += __shfl_xor(a1.x, m); a1.y += __shfl_xor(a1.y, m);
        a1.z += __shfl_xor(a1.z, m); a1.w += __shfl_xor(a1.w, m);
    }
    if (g == 0) {
        float sl = dd * dd;
        float4 h0 = H4[(long long)node * 16 + 2 * c];
        float4 h1 = H4[(long long)node * 16 + 2 * c + 1];
        float4 bb0 = b4[2 * c], bb1 = b4[2 * c + 1];
        a0.x += h0.x * sl + bb0.x; a0.y += h0.y * sl + bb0.y;
        a0.z += h0.z * sl + bb0.z; a0.w += h0.w * sl + bb0.w;
        a1.x += h1.x * sl + bb1.x; a1.y += h1.y * sl + bb1.y;
        a1.z += h1.z * sl + bb1.z; a1.w += h1.w * sl + bb1.w;
        if (RELU) {
            a0.x = fmaxf(a0.x, 0.f); a0.y = fmaxf(a0.y, 0.f);
            a0.z = fmaxf(a0.z, 0.f); a0.w = fmaxf(a0.w, 0.f);
            a1.x = fmaxf(a1.x, 0.f); a1.y = fmaxf(a1.y, 0.f);
            a1.z = fmaxf(a1.z, 0.f); a1.w = fmaxf(a1.w, 0.f);
        }
        out4[(long long)node * 16 + 2 * c] = a0;
        out4[(long long)node * 16 + 2 * c + 1] = a1;
    }
}

// ---------------- F=16: 16 edge-groups x 4 chunks per wave ----------------
template<bool RELU>
__global__ __launch_bounds__(256) void agg16_kernel(const float4* __restrict__ H4,
                                                    const int* __restrict__ rowptr,
                                                    const int* __restrict__ csr_src,
                                                    const float* __restrict__ dis,
                                                    const float4* __restrict__ b4,
                                                    float4* __restrict__ out4, int N) {
    int node = blockIdx.x * 4 + (threadIdx.x >> 6);
    int lane = threadIdx.x & 63;
    int g = lane >> 2, c = lane & 3;
    if (node >= N) return;
    float dd = dis[node];
    int i0 = (node == 0) ? 0 : rowptr[node - 1];
    int i1 = rowptr[node];
    float4 acc = {0.f, 0.f, 0.f, 0.f};
    for (int i = i0 + g; i < i1; i += 16) {
        int s = csr_src[i];
        float w = dis[s] * dd;
        float4 v = H4[(long long)s * 4 + c];
        acc.x += v.x * w; acc.y += v.y * w;
        acc.z += v.z * w; acc.w += v.w * w;
    }
#pragma unroll
    for (int m = 4; m <= 32; m <<= 1) {
        acc.x += __shfl_xor(acc.x, m);
        acc.y += __shfl_xor(acc.y, m);
        acc.z += __shfl_xor(acc.z, m);
        acc.w += __shfl_xor(acc.w, m);
    }
    if (g == 0) {
        float4 h = H4[(long long)node * 4 + c];
        float sl = dd * dd;
        float4 bb = b4[c];
        acc.x += h.x * sl + bb.x; acc.y += h.y * sl + bb.y;
        acc.z += h.z * sl + bb.z; acc.w += h.w * sl + bb.w;
        if (RELU) {
            acc.x = fmaxf(acc.x, 0.f); acc.y = fmaxf(acc.y, 0.f);
            acc.z = fmaxf(acc.z, 0.f); acc.w = fmaxf(acc.w, 0.f);
        }
        out4[(long long)node * 4 + c] = acc;
    }
}

// ---------------- pooling: register runs -> LDS bins -> few global atomics ----
__global__ __launch_bounds__(256) void pool_kernel(const float4* __restrict__ H4,
                                                   const int* __restrict__ batch,
                                                   float* __restrict__ sums,
                                                   float* __restrict__ cnts, int N) {
    __shared__ float sBin[16][16];
    __shared__ float sCnt[16];
    const int t = threadIdx.x;
    sBin[t >> 4][t & 15] = 0.f;
    if (t < 16) sCnt[t] = 0.f;
    __syncthreads();
    const int n0 = blockIdx.x * 256;
    const int g0 = batch[n0];
    const int nl = t >> 2;     // node lane 0..63
    const int f4 = t & 3;      // float4 chunk 0..3
    float4 acc = {0.f, 0.f, 0.f, 0.f};
    float cnt = 0.f;
    int curli = -1;
    for (int j = 0; j < 4; ++j) {
        int node = n0 + nl * 4 + j;
        if (node >= N) break;
        int li = batch[node] - g0;
        if (li != curli) {
            if (curli >= 0) {
                if (curli < 16) {
                    float* bp = &sBin[curli][f4 * 4];
                    atomicAdd(bp + 0, acc.x); atomicAdd(bp + 1, acc.y);
                    atomicAdd(bp + 2, acc.z); atomicAdd(bp + 3, acc.w);
                    if (f4 == 0) atomicAdd(&sCnt[curli], cnt);
                } else {
                    float* gp = &sums[(g0 + curli) * OUTF + f4 * 4];
                    atomicAdd(gp + 0, acc.x); atomicAdd(gp + 1, acc.y);
                    atomicAdd(gp + 2, acc.z); atomicAdd(gp + 3, acc.w);
                    if (f4 == 0) atomicAdd(&cnts[g0 + curli], cnt);
                }
            }
            acc.x = acc.y = acc.z = acc.w = 0.f; cnt = 0.f; curli = li;
        }
        float4 v = H4[(long long)node * 4 + f4];
        acc.x += v.x; acc.y += v.y; acc.z += v.z; acc.w += v.w;
        cnt += 1.f;
    }
    if (curli >= 0) {
        if (curli < 16) {
            float* bp = &sBin[curli][f4 * 4];
            atomicAdd(bp + 0, acc.x); atomicAdd(bp + 1, acc.y);
            atomicAdd(bp + 2, acc.z); atomicAdd(bp + 3, acc.w);
            if (f4 == 0) atomicAdd(&sCnt[curli], cnt);
        } else {
            float* gp = &sums[(g0 + curli) * OUTF + f4 * 4];
            atomicAdd(gp + 0, acc.x); atomicAdd(gp + 1, acc.y);
            atomicAdd(gp + 2, acc.z); atomicAdd(gp + 3, acc.w);
            if (f4 == 0) atomicAdd(&cnts[g0 + curli], cnt);
        }
    }
    __syncthreads();
    int bg = t >> 4, bf = t & 15;
    int g = g0 + bg;
    if (g < NGRAPH) {
        float v = sBin[bg][bf];
        if (v != 0.f) atomicAdd(&sums[g * OUTF + bf], v);
        if (bf == 0) {
            float c = sCnt[bg];
            if (c != 0.f) atomicAdd(&cnts[g], c);
        }
    }
}

__global__ void divide_kernel(const float* __restrict__ sums, const float* __restrict__ counts,
                              float* __restrict__ out) {
    int i = blockIdx.x * blockDim.x + threadIdx.x;
    if (i < NGRAPH * OUTF) out[i] = sums[i] / fmaxf(counts[i >> 4], 1.0f);
}

extern "C" void kernel_launch(void* const* d_in, const int* in_sizes, int n_in,
                              void* d_out, int out_size, void* d_ws, size_t ws_size,
                              hipStream_t stream) {
    const float* x     = (const float*)d_in[0];
    const int*   ei    = (const int*)d_in[1];
    const int*   batch = (const int*)d_in[2];
    const float* W1 = (const float*)d_in[3];
    const float* b1 = (const float*)d_in[4];
    const float* W2 = (const float*)d_in[5];
    const float* b2 = (const float*)d_in[6];
    const float* W3 = (const float*)d_in[7];
    const float* b3 = (const float*)d_in[8];
    float* out = (float*)d_out;

    const int N = in_sizes[2];          // 100000
    const int E = in_sizes[1] / 2;      // 1200000
    const int* src = ei;
    const int* dst = ei + E;

    // workspace layout (4-byte units)
    float* ws      = (float*)d_ws;
    float* dis     = ws;                          // N floats
    float* bufA    = dis + N;                     // N*64
    float* bufB    = bufA + (size_t)N * HID;      // N*64
    float* sums    = bufB + (size_t)N * HID;      // 500*16
    float* cnts    = sums + NGRAPH * OUTF;        // 500
    int*   degi    = (int*)(cnts + NGRAPH);       // N ints
    int*   rowptr  = degi + N;                    // N ints
    int*   csr_src = rowptr + N;                  // E ints
    int*   aux     = csr_src + E;                 // <=128 ints

    const int B = 256;
    const int nb = (N + 1023) / 1024;
    constexpr int EPT = 8;
    const int eblocks = (E + B * EPT - 1) / (B * EPT);

    // ---- degree, dis, CSR build ----
    hipMemsetAsync(degi, 0, (size_t)N * sizeof(int), stream);
    deg_kernel<EPT><<<eblocks, B, 0, stream>>>(dst, degi, E);
    dis_kernel<<<(N + B - 1) / B, B, 0, stream>>>(degi, dis, N);
    scan1_kernel<<<nb, 1024, 0, stream>>>(degi, rowptr, aux, N);
    scan2_kernel<<<1, 128, 0, stream>>>(aux, nb);
    scan3_kernel<<<nb, 1024, 0, stream>>>(rowptr, aux, N);
    fill_kernel<EPT><<<eblocks, B, 0, stream>>>(src, dst, rowptr, csr_src, E);

    // ---- layer 1 ----
    gemm_kernel<IN_DIM, HID><<<(N + 15) / 16, B, 0, stream>>>(x, W1, bufA, N);
    agg64_kernel<true><<<(N + 3) / 4, B, 0, stream>>>((const float4*)bufA, rowptr, csr_src,
                                                      dis, (const float4*)b1, (float4*)bufB, N);

    // ---- layer 2 ----
    gemm_kernel<HID, HID><<<(N + 15) / 16, B, 0, stream>>>(bufB, W2, bufA, N);
    agg64_kernel<true><<<(N + 3) / 4, B, 0, stream>>>((const float4*)bufA, rowptr, csr_src,
                                                      dis, (const float4*)b2, (float4*)bufB, N);

    // ---- layer 3 ----
    gemm_kernel<HID, OUTF><<<(N + 63) / 64, B, 0, stream>>>(bufB, W3, bufA, N);
    agg16_kernel<false><<<(N + 3) / 4, B, 0, stream>>>((const float4*)bufA, rowptr, csr_src,
                                                       dis, (const float4*)b3, (float4*)bufB, N);

    // ---- global mean pool ----
    hipMemsetAsync(sums, 0, (NGRAPH * OUTF + NGRAPH) * sizeof(float), stream);
    pool_kernel<<<(N + 255) / 256, B, 0, stream>>>((const float4*)bufB, batch, sums, cnts, N);
    divide_kernel<<<(NGRAPH * OUTF + B - 1) / B, B, 0, stream>>>(sums, cnts, out);
}